// Round 1
// baseline (10222.048 us; speedup 1.0000x reference)
//
#include <hip/hip_runtime.h>

// DKVMN fused forward. One block per batch element (grid=256=#CUs), 512 threads.
// Time-blocked recurrence: U=8 steps per streaming pass over the (N,DV) memory
// state, which lives in d_ws (B*N*DV fp32 = 128 MB, L3-resident).
// Pass 0 reads the initial state directly from value_memory (ws is poisoned).

#define B_ 256
#define T_ 512
#define N_ 512
#define DK_ 64
#define DV_ 256
#define S_ 64
#define F_ 64
#define U_ 8
#define NT 512
#define NPASS (T_ / U_)

__device__ __forceinline__ float dot4(float4 a, float4 b) {
  return a.x * b.x + a.y * b.y + a.z * b.z + a.w * b.w;
}

__global__ __launch_bounds__(NT, 2) void dkvmn_kernel(
    const int* __restrict__ concepts, const int* __restrict__ interactions,
    const float* __restrict__ Kmem, const float* __restrict__ Vmem,
    const float* __restrict__ cemb, const float* __restrict__ iemb,
    const float* __restrict__ We, const float* __restrict__ be,
    const float* __restrict__ Wa, const float* __restrict__ ba,
    const float* __restrict__ W1, const float* __restrict__ b1,
    const float* __restrict__ W2, const float* __restrict__ b2,
    const float* __restrict__ W3, const float* __restrict__ b3,
    float* __restrict__ out, float* __restrict__ state) {
  __shared__ float s_q[U_][DK_];   // concept embeds for U steps
  __shared__ float s_w[U_][N_];    // attention weights (logits -> softmax in place)
  __shared__ float s_v[U_][DV_];   // interaction embeds
  __shared__ float s_e[U_][DV_];   // erase gates
  __shared__ float s_a[U_][DV_];   // add vectors
  __shared__ float s_r[U_][DV_];   // read vectors (accumulated)
  __shared__ float s_h1[U_][S_];
  __shared__ float s_h2[U_][F_];

  const int tid = threadIdx.x;
  const int b = blockIdx.x;
  const int lane = tid & 63;
  const int wid = tid >> 6;  // 8 waves; wave wid owns timestep u=wid in per-step phases
  float* stb = state + (size_t)b * (N_ * DV_);

  for (int pass = 0; pass < NPASS; ++pass) {
    const int t0 = pass * U_;
    __syncthreads();  // protect s_q/s_v/s_r/s_w from previous pass readers

    // ---- stage q (U x DK, exactly 512 elems) and v (U x DV); zero r ----
    {
      const int c = concepts[b * T_ + t0 + wid];
      s_q[wid][lane] = (c != 0) ? cemb[c * DK_ + lane] : 0.f;
    }
    for (int idx = tid; idx < U_ * DV_; idx += NT) {
      const int u = idx >> 8, d = idx & (DV_ - 1);
      const int iv = interactions[b * T_ + t0 + u];
      s_v[u][d] = (iv != 0) ? iemb[iv * DV_ + d] : 0.f;
      (&s_r[0][0])[idx] = 0.f;
    }
    __syncthreads();

    // ---- logits: s_w[u][n] = q_u . K_n ----
    for (int idx = tid; idx < U_ * N_; idx += NT) {
      const int u = idx >> 9, n = idx & (N_ - 1);
      const float4* kr = (const float4*)(Kmem + n * DK_);
      const float4* qr = (const float4*)(&s_q[u][0]);
      float acc = 0.f;
#pragma unroll
      for (int kk = 0; kk < DK_ / 4; ++kk) acc += dot4(kr[kk], qr[kk]);
      s_w[u][n] = acc;
    }
    __syncthreads();

    // ---- softmax over N, wave wid handles u=wid ----
    {
      const int u = wid;
      float mx = -1e30f;
      for (int n = lane; n < N_; n += 64) mx = fmaxf(mx, s_w[u][n]);
      for (int off = 32; off > 0; off >>= 1) mx = fmaxf(mx, __shfl_xor(mx, off, 64));
      float sum = 0.f;
      for (int n = lane; n < N_; n += 64) {
        const float ex = expf(s_w[u][n] - mx);
        s_w[u][n] = ex;
        sum += ex;
      }
      for (int off = 32; off > 0; off >>= 1) sum += __shfl_xor(sum, off, 64);
      const float inv = 1.f / sum;
      for (int n = lane; n < N_; n += 64) s_w[u][n] *= inv;
    }

    // ---- erase/add gates: thread owns output dim d for 4 timesteps ----
    {
      const int d = tid & (DV_ - 1), g = tid >> 8;
      const int ub = g * 4;
      float ae[4] = {0, 0, 0, 0}, aa[4] = {0, 0, 0, 0};
      const float4* wer = (const float4*)(We + d * DV_);
      const float4* war = (const float4*)(Wa + d * DV_);
      for (int kk = 0; kk < DV_ / 4; ++kk) {
        const float4 wev = wer[kk], wav = war[kk];
#pragma unroll
        for (int uu = 0; uu < 4; ++uu) {
          const float4 vv = *(const float4*)(&s_v[ub + uu][kk * 4]);
          ae[uu] += dot4(wev, vv);
          aa[uu] += dot4(wav, vv);
        }
      }
      const float bed = be[d], bad = ba[d];
#pragma unroll
      for (int uu = 0; uu < 4; ++uu) {
        s_e[ub + uu][d] = 1.f / (1.f + expf(-(ae[uu] + bed)));
        s_a[ub + uu][d] = tanhf(aa[uu] + bad);
      }
    }
    __syncthreads();

    // ---- main stream: wave wid owns row n = nb+wid (1KB contiguous / wave),
    //      lane owns float4 chunk d4=lane; U steps applied per element in regs ----
    {
      const int d4 = lane;
      float4 e_reg[U_], a_reg[U_], racc[U_];
#pragma unroll
      for (int u = 0; u < U_; ++u) {
        e_reg[u] = *(const float4*)(&s_e[u][d4 * 4]);
        a_reg[u] = *(const float4*)(&s_a[u][d4 * 4]);
        racc[u] = make_float4(0.f, 0.f, 0.f, 0.f);
      }
      const float4* src = (pass == 0) ? (const float4*)Vmem : (const float4*)stb;
      float4* dst = (float4*)stb;
      for (int nb = 0; nb < N_; nb += 8) {
        const int n = nb + wid;
        float4 m = src[n * (DV_ / 4) + d4];
#pragma unroll
        for (int u = 0; u < U_; ++u) {
          const float wv = s_w[u][n];
          // r_t uses M_t (pre-update)
          racc[u].x = fmaf(wv, m.x, racc[u].x);
          racc[u].y = fmaf(wv, m.y, racc[u].y);
          racc[u].z = fmaf(wv, m.z, racc[u].z);
          racc[u].w = fmaf(wv, m.w, racc[u].w);
          // M <- M*(1 - w*e) + w*a  ==  M - w*(e*M - a)   (2 fma/elem)
          m.x = fmaf(-wv, fmaf(e_reg[u].x, m.x, -a_reg[u].x), m.x);
          m.y = fmaf(-wv, fmaf(e_reg[u].y, m.y, -a_reg[u].y), m.y);
          m.z = fmaf(-wv, fmaf(e_reg[u].z, m.z, -a_reg[u].z), m.z);
          m.w = fmaf(-wv, fmaf(e_reg[u].w, m.w, -a_reg[u].w), m.w);
        }
        dst[n * (DV_ / 4) + d4] = m;
      }
#pragma unroll
      for (int u = 0; u < U_; ++u) {
        atomicAdd(&s_r[u][d4 * 4 + 0], racc[u].x);
        atomicAdd(&s_r[u][d4 * 4 + 1], racc[u].y);
        atomicAdd(&s_r[u][d4 * 4 + 2], racc[u].z);
        atomicAdd(&s_r[u][d4 * 4 + 3], racc[u].w);
      }
    }
    __syncthreads();

    // ---- MLP: wave wid owns step u=wid; lane owns output neuron ----
    {
      const int u = wid;
      float acc = b1[lane];
      const float4* w1r = (const float4*)(W1 + lane * (DV_ + DK_));
#pragma unroll
      for (int kk = 0; kk < DV_ / 4; ++kk)
        acc += dot4(w1r[kk], *(const float4*)(&s_r[u][kk * 4]));
#pragma unroll
      for (int kk = 0; kk < DK_ / 4; ++kk)
        acc += dot4(w1r[DV_ / 4 + kk], *(const float4*)(&s_q[u][kk * 4]));
      s_h1[u][lane] = fmaxf(acc, 0.f);
    }
    __syncthreads();
    {
      const int u = wid;
      float acc = b2[lane];
      const float4* w2r = (const float4*)(W2 + lane * S_);
#pragma unroll
      for (int kk = 0; kk < S_ / 4; ++kk)
        acc += dot4(w2r[kk], *(const float4*)(&s_h1[u][kk * 4]));
      s_h2[u][lane] = fmaxf(acc, 0.f);
    }
    __syncthreads();
    {
      const int u = wid;
      float p = s_h2[u][lane] * W3[lane];
      for (int off = 32; off > 0; off >>= 1) p += __shfl_xor(p, off, 64);
      if (lane == 0)
        out[(size_t)b * T_ + t0 + u] = 1.f / (1.f + expf(-(p + b3[0])));
    }
  }
}

extern "C" void kernel_launch(void* const* d_in, const int* in_sizes, int n_in,
                              void* d_out, int out_size, void* d_ws, size_t ws_size,
                              hipStream_t stream) {
  const int* concepts = (const int*)d_in[0];
  const int* interactions = (const int*)d_in[1];
  const float* Kmem = (const float*)d_in[2];
  const float* Vmem = (const float*)d_in[3];
  const float* cemb = (const float*)d_in[4];
  const float* iemb = (const float*)d_in[5];
  const float* We = (const float*)d_in[6];
  const float* be = (const float*)d_in[7];
  const float* Wa = (const float*)d_in[8];
  const float* ba = (const float*)d_in[9];
  const float* W1 = (const float*)d_in[10];
  const float* b1 = (const float*)d_in[11];
  const float* W2 = (const float*)d_in[12];
  const float* b2 = (const float*)d_in[13];
  const float* W3 = (const float*)d_in[14];
  const float* b3 = (const float*)d_in[15];
  float* out = (float*)d_out;
  float* state = (float*)d_ws;  // B*N*DV fp32 = 128 MiB

  dkvmn_kernel<<<dim3(B_), dim3(NT), 0, stream>>>(
      concepts, interactions, Kmem, Vmem, cemb, iemb, We, be, Wa, ba,
      W1, b1, W2, b2, W3, b3, out, state);
}